// Round 16
// baseline (166.808 us; speedup 1.0000x reference)
//
#include <hip/hip_runtime.h>
#include <hip/hip_bf16.h>

#define NEG (-1e30f)
#define M_ROWS 8000   // B*T = 16*500
#define N_COLS 5000   // V
#define K_DIM  256    // D
#define T_LEN  500
#define T_PAD  512    // lgT inner stride (t)
#define B_SZ   16
#define L_LAB  50
#define DP_STR  516   // k_dp LDS row stride (dwords)
#define N_TILES 640   // 32 x 20 tiles of 256x256
#define GRID_P  512   // persistent grid = 2 blocks/CU x 256 CU (exact capacity)
#define LOG2E   1.4426950408889634f
#define LN2     0.6931471805599453f

typedef _Float16 half8  __attribute__((ext_vector_type(8)));
typedef _Float16 half4v __attribute__((ext_vector_type(4)));
typedef float    floatx4 __attribute__((ext_vector_type(4)));

__device__ __forceinline__ float fexp2(float x) {
#if defined(__has_builtin)
#if __has_builtin(__builtin_amdgcn_exp2f)
  return __builtin_amdgcn_exp2f(x);
#else
  return __expf(x * LN2);
#endif
#else
  return __expf(x * LN2);
#endif
}
__device__ __forceinline__ float flog2(float x) {
#if defined(__has_builtin)
#if __has_builtin(__builtin_amdgcn_logf)
  return __builtin_amdgcn_logf(x);
#else
  return __logf(x) * LOG2E;
#endif
#else
  return __logf(x) * LOG2E;
#endif
}
__device__ __forceinline__ float wave_shr1(float x, float fill) {
#if defined(__has_builtin)
#if __has_builtin(__builtin_amdgcn_update_dpp)
  int r = __builtin_amdgcn_update_dpp(__float_as_int(fill), __float_as_int(x),
                                      0x138 /*wave_shr:1*/, 0xf, 0xf, false);
  return __int_as_float(r);
#else
  return __shfl_up(x, 1);
#endif
#else
  return __shfl_up(x, 1);
#endif
}

// async global->LDS, 16B per lane (dest = wave-uniform base + lane*16)
__device__ __forceinline__ void gload_lds16(const _Float16* g, _Float16* l) {
  __builtin_amdgcn_global_load_lds(
      (const __attribute__((address_space(1))) void*)g,
      (__attribute__((address_space(3))) void*)l,
      16, 0, 0);
}

// ---------------- fused fp32->fp16 (enc + W) + zero out/psum + seed counter -------
__global__ void k_f2h2(const float* __restrict__ enc, const float* __restrict__ W,
                       _Float16* __restrict__ ench, _Float16* __restrict__ wh,
                       float* z, float* psum, int* __restrict__ tcnt) {
  int i = blockIdx.x * blockDim.x + threadIdx.x;
  if (i == 0) z[0] = 0.0f;
  if (i == 1) tcnt[0] = GRID_P;   // next-tile pointer (tiles 0..GRID_P-1 pre-assigned)
  if (i < M_ROWS) psum[i] = 0.0f;
  if (i < 512000) {
    float4 v = ((const float4*)enc)[i];
    half4v o = {(_Float16)v.x, (_Float16)v.y, (_Float16)v.z, (_Float16)v.w};
    ((half4v*)ench)[i] = o;
  } else {
    int k = i - 512000;
    if (k < 320000) {
      float4 v = ((const float4*)W)[k];
      half4v o = {(_Float16)v.x, (_Float16)v.y, (_Float16)v.z, (_Float16)v.w};
      ((half4v*)wh)[k] = o;
    }
  }
}

// ---------------- MFMA GEMM + fused sumexp + ballot label-logit scatter ------------
// R18 = R17 tile body (gemm 48.5us, VGPR 64, conflicts 0) made PERSISTENT with
// dynamic work-stealing. Diagnosis: 640 blocks at 2-resident/CU = round 1 (512
// blocks, all CUs) + round 2 (128 blocks, 64 CUs; 192 CUs IDLE) -> makespan 4
// block-units for 2.5 units/CU of work (~38% structural waste; fits occupancy
// ~30% at exact-capacity residency, and why per-block schedule changes were all
// null while block-count changes moved 74->61->57->48.5). Fix: grid = 512
// (exact 2/CU capacity), each block loops over tiles via atomicAdd counter
// (seeded to 512 by k_f2h2; first tile = blockIdx). No inter-block ordering
// assumed (tiles independent) -> dispatch-order-safe. vmcnt ledger valid across
// tiles: epilogue stores are OLDER in the vmcnt FIFO than next tile's stage
// issues, so vmcnt(2) retires them first (in-order counter retire).
__global__ __launch_bounds__(1024) void k_gemm_lse(
    const _Float16* __restrict__ A, const _Float16* __restrict__ Bm,
    const float* __restrict__ bias, const int* __restrict__ y,
    float* __restrict__ psum, float* __restrict__ lgT, int* __restrict__ tcnt) {
  __shared__ _Float16 As[2 * 256 * 32];   // 32 KB (2 buffers)
  __shared__ _Float16 Bs[2 * 256 * 32];   // 32 KB
  __shared__ float sPS[4 * 256];          // 4 KB: per-wave_n partial row sums
  __shared__ int sNext;

  const int tid = threadIdx.x;
  const int lane = tid & 63;
  const int wid = tid >> 6;                        // 0..15
  const int wave_m = wid & 3, wave_n = wid >> 2;   // 4x4 waves of 64x64
  const int l15 = lane & 15, quad = lane >> 4;

  // staging geometry (BK=32): one gload_lds16 covers 16 rows x 4 chunks (1 KB).
  const int lrow = lane >> 2;                              // row within 16-row group
  const int co = (((lane & 3) ^ ((lane >> 3) & 3)) * 8);   // swizzled src chunk (halfs)
  const int rsw2 = (l15 >> 1) & 3;                         // reader chunk XOR

  int tile = blockIdx.x;   // first tile pre-assigned; steal the rest

  while (true) {
    // XCD-style swizzle on tile index (640 % 8 == 0 -> bijective)
    const int wg = (tile & 7) * 80 + (tile >> 3);
    const int n0 = (wg % 20) * 256;
    const int m0 = (wg / 20) * 256;

    floatx4 acc[4][4];
    floatx4 zz = {0.f, 0.f, 0.f, 0.f};
    #pragma unroll
    for (int mi = 0; mi < 4; ++mi)
      #pragma unroll
      for (int ni = 0; ni < 4; ++ni) acc[mi][ni] = zz;

    auto stage = [&](int kk, int buf) {
      {                                      // A: 16 groups of 16 rows / 16 waves
        const int g = wid;
        const int r = g * 16 + lrow;
        int ga = m0 + r; if (ga > M_ROWS - 1) ga = M_ROWS - 1;
        gload_lds16(A + (size_t)ga * K_DIM + kk * 32 + co, As + buf * 8192 + g * 512);
      }
      {                                      // B: 16 groups / 16 waves
        const int g = wid;
        const int r = g * 16 + lrow;
        int gb = n0 + r; if (gb > N_COLS - 1) gb = N_COLS - 1;
        gload_lds16(Bm + (size_t)gb * K_DIM + kk * 32 + co, Bs + buf * 8192 + g * 512);
      }
    };

    // prologue: tiles 0 and 1 in flight (2 vm-ops each per wave)
    stage(0, 0);
    stage(1, 1);

    #pragma unroll
    for (int kk = 0; kk < 8; ++kk) {
      const int cur = kk & 1;
      if (kk < 7) asm volatile("s_waitcnt vmcnt(2)" ::: "memory");  // tile kk landed
      else        asm volatile("s_waitcnt vmcnt(0)" ::: "memory");  // last tile
      __builtin_amdgcn_s_barrier();          // all waves: tile kk resident

      half8 af[4], bf[4];
      #pragma unroll
      for (int mi = 0; mi < 4; ++mi)
        af[mi] = *(const half8*)(As + cur * 8192 + (wave_m * 64 + mi * 16 + l15) * 32 + ((quad ^ rsw2) << 3));
      #pragma unroll
      for (int ni = 0; ni < 4; ++ni)
        bf[ni] = *(const half8*)(Bs + cur * 8192 + (wave_n * 64 + ni * 16 + l15) * 32 + ((quad ^ rsw2) << 3));

      asm volatile("s_waitcnt lgkmcnt(0)" ::: "memory");  // my reads of buf cur done
      __builtin_amdgcn_sched_barrier(0);
      __builtin_amdgcn_s_barrier();          // WAR fence: ALL waves done reading buf cur
      if (kk < 6) stage(kk + 2, cur);        // overwrite cur; waited >=2 iters later

      #pragma unroll
      for (int mi = 0; mi < 4; ++mi)
        #pragma unroll
        for (int ni = 0; ni < 4; ++ni)
          acc[mi][ni] = __builtin_amdgcn_mfma_f32_16x16x32_f16(af[mi], bf[ni], acc[mi][ni], 0, 0, 0);
    }

    // ---- epilogue 1: bias + column masks ----
    float bvv[4]; bool cok[4];
    #pragma unroll
    for (int ni = 0; ni < 4; ++ni) {
      int col = n0 + wave_n * 64 + ni * 16 + l15;
      cok[ni] = (col < N_COLS);
      bvv[ni] = cok[ni] ? bias[col] : 0.f;
    }

    // ---- epilogue 2: ballot-based scatter of label logits -----------------------
    // lane j (0..50) holds ext-label j's vocab id (j=0 blank). One ballot finds
    // which labels land in this wave's 64-col window; loop only over matches.
    // C/D layout: col = lane&15, row = quad*4 + reg.
    const int nbase = n0 + wave_n * 64;
    const int mbase = m0 + wave_m * 64;
    int b_lo = mbase / T_LEN;
    int b_hi = (mbase + 63) / T_LEN;
    if (b_hi > B_SZ - 1) b_hi = B_SZ - 1;
    for (int b = b_lo; b <= b_hi; ++b) {
      int v_l = 0x40000000;
      if (lane <= 50) v_l = (lane == 0) ? 0 : y[b * L_LAB + lane - 1];
      int dv_l = v_l - nbase;
      unsigned long long mask = __ballot(dv_l >= 0 && dv_l < 64);
      while (mask) {
        int j = (int)__builtin_ctzll(mask);
        mask &= mask - 1;
        int dv = __shfl(dv_l, j);          // wave-uniform
        int ni = dv >> 4;
        float bb = bvv[0];
        bb = (ni == 1) ? bvv[1] : bb;
        bb = (ni == 2) ? bvv[2] : bb;
        bb = (ni == 3) ? bvv[3] : bb;
        if ((dv & 15) == l15) {
          #pragma unroll
          for (int mi = 0; mi < 4; ++mi) {
            #pragma unroll
            for (int r = 0; r < 4; ++r) {
              float val = acc[mi][0][r];
              val = (ni == 1) ? acc[mi][1][r] : val;
              val = (ni == 2) ? acc[mi][2][r] : val;
              val = (ni == 3) ? acc[mi][3][r] : val;
              int grow = mbase + mi * 16 + quad * 4 + r;
              int t = grow - b * T_LEN;
              if (t >= 0 && t < T_LEN && grow < M_ROWS)
                lgT[((size_t)b * 51 + j) * T_PAD + t] = val + bb;
            }
          }
        }
      }
    }

    // ---- epilogue 3: per-row sum of 2^(logit*log2e) -----------------------------
    // Partial per wave_n -> LDS pre-reduce (disjoint writes) -> ONE atomic per row
    // per tile. No max subtraction: logits O(+-10), 2^(x*log2e) fp32-safe.
    #pragma unroll
    for (int mi = 0; mi < 4; ++mi) {
      #pragma unroll
      for (int r = 0; r < 4; ++r) {
        int rw = wave_m * 64 + mi * 16 + quad * 4 + r;   // row within 256-tile
        float se = 0.f;
        se += cok[0] ? fexp2((acc[mi][0][r] + bvv[0]) * LOG2E) : 0.f;
        se += cok[1] ? fexp2((acc[mi][1][r] + bvv[1]) * LOG2E) : 0.f;
        se += cok[2] ? fexp2((acc[mi][2][r] + bvv[2]) * LOG2E) : 0.f;
        se += cok[3] ? fexp2((acc[mi][3][r] + bvv[3]) * LOG2E) : 0.f;
        #pragma unroll
        for (int d = 1; d < 16; d <<= 1) se += __shfl_xor(se, d);
        if (l15 == 0) sPS[wave_n * 256 + rw] = se;       // disjoint (wave_n, rw)
      }
    }
    __syncthreads();
    if (tid < 256) {
      int grow = m0 + tid;
      if (grow < M_ROWS) {
        float s = sPS[tid] + sPS[256 + tid] + sPS[512 + tid] + sPS[768 + tid];
        atomicAdd(&psum[grow], s);
      }
    }

    // ---- steal next tile --------------------------------------------------------
    if (tid == 0) sNext = atomicAdd(tcnt, 1);
    __syncthreads();                        // publish sNext + fence LDS reuse
    tile = sNext;
    if (tile >= N_TILES) break;
  }
}

// ---------------- CTC forward DP + fused lse sum ----------------------------------
// One block (256 thr) per batch element. All waves stage lgT[b] into LDS and
// compute sum_t log2(psum[b,t]) in parallel; wave 0 then runs the serial DP in
// base-2 domain out of LDS. (Log-domain: cross-lane alpha dynamic range
// exceeds fp32 -- prob-domain with uniform rescale measured absmax=inf, R15.)
__global__ __launch_bounds__(256) void k_dp(
    const float* __restrict__ lgT, const float* __restrict__ psum,
    const int* __restrict__ enc_lens, const int* __restrict__ y,
    const int* __restrict__ y_lens, float* __restrict__ out) {
  __shared__ float sA[51 * DP_STR];   // ~105 KB
  __shared__ float sRed[5];
  const int b = blockIdx.x, tid = threadIdx.x;
  const int Tb = enc_lens[b], yl = y_lens[b];

  // stage logits (scaled to base-2 domain)
  const float* g = lgT + (size_t)b * 51 * T_PAD;
  #pragma unroll
  for (int k = 0; k < 26; ++k) {
    int idx = tid + k * 256;
    if (idx < 51 * 128) {
      int row = idx >> 7, c4 = (idx & 127) << 2;
      float4 v = *(const float4*)(g + (size_t)row * T_PAD + c4);
      float4 s = {v.x * LOG2E, v.y * LOG2E, v.z * LOG2E, v.w * LOG2E};
      *(float4*)(sA + row * DP_STR + c4) = s;
    }
  }

  // parallel lse sum: sum_t log2(psum[b,t]), t < Tb
  float sl2 = 0.f;
  for (int t = tid; t < Tb; t += 256) sl2 += flog2(psum[b * T_LEN + t]);
  #pragma unroll
  for (int d = 1; d < 64; d <<= 1) sl2 += __shfl_xor(sl2, d);
  if ((tid & 63) == 0) sRed[1 + (tid >> 6)] = sl2;
  __syncthreads();
  const float slse = LN2 * (sRed[1] + sRed[2] + sRed[3] + sRed[4]);

  if (tid < 64) {
    const int i = tid;
    const int jj = (i + 1 < 50) ? (i + 1) : 50;
    const float* bl = sA;
    const float* ow = sA + jj * DP_STR;
    const bool v0 = (i <= 50), v1 = (i <= 49);
    const bool lane0 = (i == 0);
    const bool skip1 = (i >= 1 && i <= 49) && (y[b * L_LAB + i] != y[b * L_LAB + i - 1]);

    float4 A0 = *(const float4*)(bl + 0),  A1 = *(const float4*)(ow + 0);
    float4 B0 = *(const float4*)(bl + 4),  B1 = *(const float4*)(ow + 4);
    float4 C0 = *(const float4*)(bl + 8),  C1 = *(const float4*)(ow + 8);
    float4 D0 = *(const float4*)(bl + 12), D1 = *(const float4*)(ow + 12);
    const float4 n4 = {NEG, NEG, NEG, NEG};
    if (!v1) { A1 = n4; B1 = n4; C1 = n4; D1 = n4; }

    float a0 = lane0 ? A0.x : NEG;
    float a1 = lane0 ? A1.x : NEG;

    auto step = [&](float l0r, float l1) {
      float l0 = v0 ? l0r : NEG;
      float p1 = wave_shr1(a1, NEG);
      p1 = lane0 ? NEG : p1;
      float th = skip1 ? p1 : NEG;
      float m0 = fmaxf(a0, p1);
      float na0 = m0 + flog2(fexp2(a0 - m0) + fexp2(p1 - m0)) + l0;
      float m1 = fmaxf(fmaxf(a1, a0), th);
      float na1 = m1 + flog2(fexp2(a1 - m1) + fexp2(a0 - m1) + fexp2(th - m1)) + l1;
      a0 = na0; a1 = na1;
    };

    step(A0.y, A1.y);
    step(A0.z, A1.z);
    step(A0.w, A1.w);

    float4 c0 = B0, c1 = B1, n0v = C0, n1v = C1, nn0 = D0, nn1 = D1;
    int t = 4;
    while (t + 4 <= Tb) {
      float4 p0 = *(const float4*)(bl + t + 12);   // max 511 < 512 in-bounds
      float4 p1v = *(const float4*)(ow + t + 12);
      if (!v1) p1v = n4;
      step(c0.x, c1.x);
      step(c0.y, c1.y);
      step(c0.z, c1.z);
      step(c0.w, c1.w);
      c0 = n0v; c1 = n1v; n0v = nn0; n1v = nn1; nn0 = p0; nn1 = p1v;
      t += 4;
    }
    if (t < Tb) { step(c0.x, c1.x); ++t; }
    if (t < Tb) { step(c0.y, c1.y); ++t; }
    if (t < Tb) { step(c0.z, c1.z); ++t; }

    float ea = __shfl(a0, yl);       // s = 2*yl
    float eb = __shfl(a1, yl - 1);   // s = 2*yl-1
    if (lane0) {
      float m = fmaxf(ea, eb);
      float fin = LN2 * (m + flog2(fexp2(ea - m) + fexp2(eb - m)));
      atomicAdd(out, (slse - fin) * (1.0f / (float)B_SZ));
    }
  }
}

extern "C" void kernel_launch(void* const* d_in, const int* in_sizes, int n_in,
                              void* d_out, int out_size, void* d_ws, size_t ws_size,
                              hipStream_t stream) {
  (void)in_sizes; (void)n_in; (void)out_size; (void)ws_size;
  const float* enc      = (const float*)d_in[0];   // [16][500][256]
  const int*   enc_lens = (const int*)d_in[1];     // [16]
  const int*   y        = (const int*)d_in[2];     // [16][50]
  const int*   y_lens   = (const int*)d_in[3];     // [16]
  const float* W        = (const float*)d_in[4];   // [5000][256]
  const float* bias     = (const float*)d_in[5];   // [5000]
  float* out = (float*)d_out;

  char* ws = (char*)d_ws;
  _Float16* ench = (_Float16*)(ws + 0);            // 4,096,000 B
  _Float16* wh   = (_Float16*)(ws + 4096000);      // 2,560,000 B
  float* psum    = (float*)(ws + 6656000);         //    32,000 B
  float* lgT     = (float*)(ws + 6688000);         // 16*51*512*4 = 1,671,168 B
  int*   tcnt    = (int*)(ws + 8359168);           //         4 B work-steal counter

  k_f2h2<<<3250, 256, 0, stream>>>(enc, W, ench, wh, out, psum, tcnt);
  k_gemm_lse<<<GRID_P, 1024, 0, stream>>>(ench, wh, bias, y, psum, lgT, tcnt);
  k_dp<<<16, 256, 0, stream>>>(lgT, psum, enc_lens, y, y_lens, out);
}

// Round 17
// 162.872 us; speedup vs baseline: 1.0242x; 1.0242x over previous
//
#include <hip/hip_runtime.h>
#include <hip/hip_bf16.h>

#define NEG (-1e30f)
#define M_ROWS 8000   // B*T = 16*500
#define N_COLS 5000   // V
#define K_DIM  256    // D
#define T_LEN  500
#define T_PAD  512    // lgT inner stride (t)
#define B_SZ   16
#define L_LAB  50
#define DP_STR  516   // k_dp LDS row stride (dwords)
#define LOG2E   1.4426950408889634f
#define LN2     0.6931471805599453f

typedef _Float16 half8  __attribute__((ext_vector_type(8)));
typedef _Float16 half4v __attribute__((ext_vector_type(4)));
typedef float    floatx4 __attribute__((ext_vector_type(4)));

__device__ __forceinline__ float fexp2(float x) {
#if defined(__has_builtin)
#if __has_builtin(__builtin_amdgcn_exp2f)
  return __builtin_amdgcn_exp2f(x);
#else
  return __expf(x * LN2);
#endif
#else
  return __expf(x * LN2);
#endif
}
__device__ __forceinline__ float flog2(float x) {
#if defined(__has_builtin)
#if __has_builtin(__builtin_amdgcn_logf)
  return __builtin_amdgcn_logf(x);
#else
  return __logf(x) * LOG2E;
#endif
#else
  return __logf(x) * LOG2E;
#endif
}
__device__ __forceinline__ float wave_shr1(float x, float fill) {
#if defined(__has_builtin)
#if __has_builtin(__builtin_amdgcn_update_dpp)
  int r = __builtin_amdgcn_update_dpp(__float_as_int(fill), __float_as_int(x),
                                      0x138 /*wave_shr:1*/, 0xf, 0xf, false);
  return __int_as_float(r);
#else
  return __shfl_up(x, 1);
#endif
#else
  return __shfl_up(x, 1);
#endif
}

// async global->LDS, 16B per lane (dest = wave-uniform base + lane*16)
__device__ __forceinline__ void gload_lds16(const _Float16* g, _Float16* l) {
  __builtin_amdgcn_global_load_lds(
      (const __attribute__((address_space(1))) void*)g,
      (__attribute__((address_space(3))) void*)l,
      16, 0, 0);
}

// ---------------- fused fp32->fp16 (enc + W) + zero out/psum ----------------------
__global__ void k_f2h2(const float* __restrict__ enc, const float* __restrict__ W,
                       _Float16* __restrict__ ench, _Float16* __restrict__ wh,
                       float* z, float* psum) {
  int i = blockIdx.x * blockDim.x + threadIdx.x;
  if (i == 0) z[0] = 0.0f;
  if (i < M_ROWS) psum[i] = 0.0f;
  if (i < 512000) {
    float4 v = ((const float4*)enc)[i];
    half4v o = {(_Float16)v.x, (_Float16)v.y, (_Float16)v.z, (_Float16)v.w};
    ((half4v*)ench)[i] = o;
  } else {
    int k = i - 512000;
    if (k < 320000) {
      float4 v = ((const float4*)W)[k];
      half4v o = {(_Float16)v.x, (_Float16)v.y, (_Float16)v.z, (_Float16)v.w};
      ((half4v*)wh)[k] = o;
    }
  }
}

// ---------------- MFMA GEMM + fused sumexp + ballot label-logit scatter ------------
// R19 = R17 exact revert (best measured: total 160.2us, gemm 48.5us, VGPR 64,
// conflicts 0, FETCH 16.9MB, WRITE 22.8MB, occ 30%).
// R18's persistent work-stealing REGRESSED (gemm 56.2, FETCH 2.7x): dynamic
// tile grab breaks tile->XCD alignment -- a pinned block steals arbitrary
// tiles, so neighbor tiles sharing B-panels no longer co-locate on one XCD's
// L2 -> panel re-reads fall to HBM. Tile->block mapping IS part of the memory
// hierarchy on MI355X; static dispatch + aligned swizzle wins.
// Structure: 256x256 tile, 16 waves x 1024 thr, BK=32 counted-vmcnt dbuf,
// bijective XCD swizzle (640 = 8*80), epilogue-3 LDS pre-reduce (1 atomic/row).
__global__ __launch_bounds__(1024) void k_gemm_lse(
    const _Float16* __restrict__ A, const _Float16* __restrict__ Bm,
    const float* __restrict__ bias, const int* __restrict__ y,
    float* __restrict__ psum, float* __restrict__ lgT) {
  __shared__ _Float16 As[2 * 256 * 32];   // 32 KB (2 buffers)
  __shared__ _Float16 Bs[2 * 256 * 32];   // 32 KB
  __shared__ float sPS[4 * 256];          // 4 KB: per-wave_n partial row sums

  const int tid = threadIdx.x;
  const int lane = tid & 63;
  const int wid = tid >> 6;                        // 0..15
  const int wave_m = wid & 3, wave_n = wid >> 2;   // 4x4 waves of 64x64
  const int l15 = lane & 15, quad = lane >> 4;

  // XCD swizzle (8 XCDs, 640 % 8 == 0 -> bijective)
  const int flat = blockIdx.x;
  const int wg = (flat & 7) * 80 + (flat >> 3);
  const int n0 = (wg % 20) * 256;
  const int m0 = (wg / 20) * 256;

  floatx4 acc[4][4];
  floatx4 zz = {0.f, 0.f, 0.f, 0.f};
  #pragma unroll
  for (int mi = 0; mi < 4; ++mi)
    #pragma unroll
    for (int ni = 0; ni < 4; ++ni) acc[mi][ni] = zz;

  // staging geometry (BK=32): one gload_lds16 covers 16 rows x 4 chunks (1 KB).
  // Lane l -> dest slot (row = g*16 + (l>>2), chunk = l&3); slot (row,c) holds
  // global chunk c ^ ((row>>1)&3) via pre-swizzled SOURCE chunk.
  const int lrow = lane >> 2;                              // row within 16-row group
  const int co = (((lane & 3) ^ ((lane >> 3) & 3)) * 8);   // swizzled src chunk (halfs)
  const int rsw2 = (l15 >> 1) & 3;                         // reader chunk XOR

  auto stage = [&](int kk, int buf) {
    {                                      // A: 16 groups of 16 rows / 16 waves
      const int g = wid;
      const int r = g * 16 + lrow;
      int ga = m0 + r; if (ga > M_ROWS - 1) ga = M_ROWS - 1;
      gload_lds16(A + (size_t)ga * K_DIM + kk * 32 + co, As + buf * 8192 + g * 512);
    }
    {                                      // B: 16 groups / 16 waves
      const int g = wid;
      const int r = g * 16 + lrow;
      int gb = n0 + r; if (gb > N_COLS - 1) gb = N_COLS - 1;
      gload_lds16(Bm + (size_t)gb * K_DIM + kk * 32 + co, Bs + buf * 8192 + g * 512);
    }
  };

  // prologue: tiles 0 and 1 in flight (2 vm-ops each per wave)
  stage(0, 0);
  stage(1, 1);

  #pragma unroll
  for (int kk = 0; kk < 8; ++kk) {
    const int cur = kk & 1;
    if (kk < 7) asm volatile("s_waitcnt vmcnt(2)" ::: "memory");  // tile kk landed
    else        asm volatile("s_waitcnt vmcnt(0)" ::: "memory");  // last tile
    __builtin_amdgcn_s_barrier();          // all waves: tile kk resident

    half8 af[4], bf[4];
    #pragma unroll
    for (int mi = 0; mi < 4; ++mi)
      af[mi] = *(const half8*)(As + cur * 8192 + (wave_m * 64 + mi * 16 + l15) * 32 + ((quad ^ rsw2) << 3));
    #pragma unroll
    for (int ni = 0; ni < 4; ++ni)
      bf[ni] = *(const half8*)(Bs + cur * 8192 + (wave_n * 64 + ni * 16 + l15) * 32 + ((quad ^ rsw2) << 3));

    asm volatile("s_waitcnt lgkmcnt(0)" ::: "memory");  // my reads of buf cur done
    __builtin_amdgcn_sched_barrier(0);
    __builtin_amdgcn_s_barrier();          // WAR fence: ALL waves done reading buf cur
    if (kk < 6) stage(kk + 2, cur);        // overwrite cur; waited >=2 iters later

    #pragma unroll
    for (int mi = 0; mi < 4; ++mi)
      #pragma unroll
      for (int ni = 0; ni < 4; ++ni)
        acc[mi][ni] = __builtin_amdgcn_mfma_f32_16x16x32_f16(af[mi], bf[ni], acc[mi][ni], 0, 0, 0);
  }

  // ---- epilogue 1: bias + column masks ----
  float bvv[4]; bool cok[4];
  #pragma unroll
  for (int ni = 0; ni < 4; ++ni) {
    int col = n0 + wave_n * 64 + ni * 16 + l15;
    cok[ni] = (col < N_COLS);
    bvv[ni] = cok[ni] ? bias[col] : 0.f;
  }

  // ---- epilogue 2: ballot-based scatter of label logits -------------------------
  // lane j (0..50) holds ext-label j's vocab id (j=0 blank). One ballot finds
  // which labels land in this wave's 64-col window; loop only over matches.
  // C/D layout: col = lane&15, row = quad*4 + reg.
  const int nbase = n0 + wave_n * 64;
  const int mbase = m0 + wave_m * 64;
  int b_lo = mbase / T_LEN;
  int b_hi = (mbase + 63) / T_LEN;
  if (b_hi > B_SZ - 1) b_hi = B_SZ - 1;
  for (int b = b_lo; b <= b_hi; ++b) {
    int v_l = 0x40000000;
    if (lane <= 50) v_l = (lane == 0) ? 0 : y[b * L_LAB + lane - 1];
    int dv_l = v_l - nbase;
    unsigned long long mask = __ballot(dv_l >= 0 && dv_l < 64);
    while (mask) {
      int j = (int)__builtin_ctzll(mask);
      mask &= mask - 1;
      int dv = __shfl(dv_l, j);          // wave-uniform
      int ni = dv >> 4;
      float bb = bvv[0];
      bb = (ni == 1) ? bvv[1] : bb;
      bb = (ni == 2) ? bvv[2] : bb;
      bb = (ni == 3) ? bvv[3] : bb;
      if ((dv & 15) == l15) {
        #pragma unroll
        for (int mi = 0; mi < 4; ++mi) {
          #pragma unroll
          for (int r = 0; r < 4; ++r) {
            float val = acc[mi][0][r];
            val = (ni == 1) ? acc[mi][1][r] : val;
            val = (ni == 2) ? acc[mi][2][r] : val;
            val = (ni == 3) ? acc[mi][3][r] : val;
            int grow = mbase + mi * 16 + quad * 4 + r;
            int t = grow - b * T_LEN;
            if (t >= 0 && t < T_LEN && grow < M_ROWS)
              lgT[((size_t)b * 51 + j) * T_PAD + t] = val + bb;
          }
        }
      }
    }
  }

  // ---- epilogue 3: per-row sum of 2^(logit*log2e) -------------------------------
  // Partial per wave_n -> LDS pre-reduce (disjoint writes) -> ONE atomic per row
  // per block (640K -> 160K device atomics). No max subtraction: logits are
  // O(+-10), 2^(x*log2e) is fp32-safe.
  #pragma unroll
  for (int mi = 0; mi < 4; ++mi) {
    #pragma unroll
    for (int r = 0; r < 4; ++r) {
      int rw = wave_m * 64 + mi * 16 + quad * 4 + r;   // row within 256-tile
      float se = 0.f;
      se += cok[0] ? fexp2((acc[mi][0][r] + bvv[0]) * LOG2E) : 0.f;
      se += cok[1] ? fexp2((acc[mi][1][r] + bvv[1]) * LOG2E) : 0.f;
      se += cok[2] ? fexp2((acc[mi][2][r] + bvv[2]) * LOG2E) : 0.f;
      se += cok[3] ? fexp2((acc[mi][3][r] + bvv[3]) * LOG2E) : 0.f;
      #pragma unroll
      for (int d = 1; d < 16; d <<= 1) se += __shfl_xor(se, d);
      if (l15 == 0) sPS[wave_n * 256 + rw] = se;       // disjoint (wave_n, rw)
    }
  }
  __syncthreads();
  if (tid < 256) {
    int grow = m0 + tid;
    if (grow < M_ROWS) {
      float s = sPS[tid] + sPS[256 + tid] + sPS[512 + tid] + sPS[768 + tid];
      atomicAdd(&psum[grow], s);
    }
  }
}

// ---------------- CTC forward DP + fused lse sum ----------------------------------
// One block (256 thr) per batch element. All waves stage lgT[b] into LDS and
// compute sum_t log2(psum[b,t]) in parallel; wave 0 then runs the serial DP in
// base-2 domain out of LDS. (Log-domain: cross-lane alpha dynamic range
// exceeds fp32 -- prob-domain with uniform rescale measured absmax=inf, R15.)
__global__ __launch_bounds__(256) void k_dp(
    const float* __restrict__ lgT, const float* __restrict__ psum,
    const int* __restrict__ enc_lens, const int* __restrict__ y,
    const int* __restrict__ y_lens, float* __restrict__ out) {
  __shared__ float sA[51 * DP_STR];   // ~105 KB
  __shared__ float sRed[5];
  const int b = blockIdx.x, tid = threadIdx.x;
  const int Tb = enc_lens[b], yl = y_lens[b];

  // stage logits (scaled to base-2 domain)
  const float* g = lgT + (size_t)b * 51 * T_PAD;
  #pragma unroll
  for (int k = 0; k < 26; ++k) {
    int idx = tid + k * 256;
    if (idx < 51 * 128) {
      int row = idx >> 7, c4 = (idx & 127) << 2;
      float4 v = *(const float4*)(g + (size_t)row * T_PAD + c4);
      float4 s = {v.x * LOG2E, v.y * LOG2E, v.z * LOG2E, v.w * LOG2E};
      *(float4*)(sA + row * DP_STR + c4) = s;
    }
  }

  // parallel lse sum: sum_t log2(psum[b,t]), t < Tb
  float sl2 = 0.f;
  for (int t = tid; t < Tb; t += 256) sl2 += flog2(psum[b * T_LEN + t]);
  #pragma unroll
  for (int d = 1; d < 64; d <<= 1) sl2 += __shfl_xor(sl2, d);
  if ((tid & 63) == 0) sRed[1 + (tid >> 6)] = sl2;
  __syncthreads();
  const float slse = LN2 * (sRed[1] + sRed[2] + sRed[3] + sRed[4]);

  if (tid < 64) {
    const int i = tid;
    const int jj = (i + 1 < 50) ? (i + 1) : 50;
    const float* bl = sA;
    const float* ow = sA + jj * DP_STR;
    const bool v0 = (i <= 50), v1 = (i <= 49);
    const bool lane0 = (i == 0);
    const bool skip1 = (i >= 1 && i <= 49) && (y[b * L_LAB + i] != y[b * L_LAB + i - 1]);

    float4 A0 = *(const float4*)(bl + 0),  A1 = *(const float4*)(ow + 0);
    float4 B0 = *(const float4*)(bl + 4),  B1 = *(const float4*)(ow + 4);
    float4 C0 = *(const float4*)(bl + 8),  C1 = *(const float4*)(ow + 8);
    float4 D0 = *(const float4*)(bl + 12), D1 = *(const float4*)(ow + 12);
    const float4 n4 = {NEG, NEG, NEG, NEG};
    if (!v1) { A1 = n4; B1 = n4; C1 = n4; D1 = n4; }

    float a0 = lane0 ? A0.x : NEG;
    float a1 = lane0 ? A1.x : NEG;

    auto step = [&](float l0r, float l1) {
      float l0 = v0 ? l0r : NEG;
      float p1 = wave_shr1(a1, NEG);
      p1 = lane0 ? NEG : p1;
      float th = skip1 ? p1 : NEG;
      float m0 = fmaxf(a0, p1);
      float na0 = m0 + flog2(fexp2(a0 - m0) + fexp2(p1 - m0)) + l0;
      float m1 = fmaxf(fmaxf(a1, a0), th);
      float na1 = m1 + flog2(fexp2(a1 - m1) + fexp2(a0 - m1) + fexp2(th - m1)) + l1;
      a0 = na0; a1 = na1;
    };

    step(A0.y, A1.y);
    step(A0.z, A1.z);
    step(A0.w, A1.w);

    float4 c0 = B0, c1 = B1, n0v = C0, n1v = C1, nn0 = D0, nn1 = D1;
    int t = 4;
    while (t + 4 <= Tb) {
      float4 p0 = *(const float4*)(bl + t + 12);   // max 511 < 512 in-bounds
      float4 p1v = *(const float4*)(ow + t + 12);
      if (!v1) p1v = n4;
      step(c0.x, c1.x);
      step(c0.y, c1.y);
      step(c0.z, c1.z);
      step(c0.w, c1.w);
      c0 = n0v; c1 = n1v; n0v = nn0; n1v = nn1; nn0 = p0; nn1 = p1v;
      t += 4;
    }
    if (t < Tb) { step(c0.x, c1.x); ++t; }
    if (t < Tb) { step(c0.y, c1.y); ++t; }
    if (t < Tb) { step(c0.z, c1.z); ++t; }

    float ea = __shfl(a0, yl);       // s = 2*yl
    float eb = __shfl(a1, yl - 1);   // s = 2*yl-1
    if (lane0) {
      float m = fmaxf(ea, eb);
      float fin = LN2 * (m + flog2(fexp2(ea - m) + fexp2(eb - m)));
      atomicAdd(out, (slse - fin) * (1.0f / (float)B_SZ));
    }
  }
}

extern "C" void kernel_launch(void* const* d_in, const int* in_sizes, int n_in,
                              void* d_out, int out_size, void* d_ws, size_t ws_size,
                              hipStream_t stream) {
  (void)in_sizes; (void)n_in; (void)out_size; (void)ws_size;
  const float* enc      = (const float*)d_in[0];   // [16][500][256]
  const int*   enc_lens = (const int*)d_in[1];     // [16]
  const int*   y        = (const int*)d_in[2];     // [16][50]
  const int*   y_lens   = (const int*)d_in[3];     // [16]
  const float* W        = (const float*)d_in[4];   // [5000][256]
  const float* bias     = (const float*)d_in[5];   // [5000]
  float* out = (float*)d_out;

  char* ws = (char*)d_ws;
  _Float16* ench = (_Float16*)(ws + 0);            // 4,096,000 B
  _Float16* wh   = (_Float16*)(ws + 4096000);      // 2,560,000 B
  float* psum    = (float*)(ws + 6656000);         //    32,000 B
  float* lgT     = (float*)(ws + 6688000);         // 16*51*512*4 = 1,671,168 B

  k_f2h2<<<3250, 256, 0, stream>>>(enc, W, ench, wh, out, psum);
  k_gemm_lse<<<640, 1024, 0, stream>>>(ench, wh, bias, y, psum, lgT);
  k_dp<<<16, 256, 0, stream>>>(lgT, psum, enc_lens, y, y_lens, out);
}

// Round 18
// 154.651 us; speedup vs baseline: 1.0786x; 1.0532x over previous
//
#include <hip/hip_runtime.h>
#include <hip/hip_bf16.h>

#define NEG (-1e30f)
#define M_ROWS 8000   // B*T = 16*500
#define N_COLS 5000   // V
#define K_DIM  256    // D
#define T_LEN  500
#define T_PAD  512    // lgT inner stride (t)
#define B_SZ   16
#define L_LAB  50
#define DP_STR  516   // k_dp LDS row stride (dwords)
#define LOG2E   1.4426950408889634f
#define LN2     0.6931471805599453f

typedef _Float16 half8  __attribute__((ext_vector_type(8)));
typedef _Float16 half4v __attribute__((ext_vector_type(4)));
typedef float    floatx4 __attribute__((ext_vector_type(4)));

__device__ __forceinline__ float fexp2(float x) {
#if defined(__has_builtin)
#if __has_builtin(__builtin_amdgcn_exp2f)
  return __builtin_amdgcn_exp2f(x);
#else
  return __expf(x * LN2);
#endif
#else
  return __expf(x * LN2);
#endif
}
__device__ __forceinline__ float flog2(float x) {
#if defined(__has_builtin)
#if __has_builtin(__builtin_amdgcn_logf)
  return __builtin_amdgcn_logf(x);
#else
  return __logf(x) * LOG2E;
#endif
#else
  return __logf(x) * LOG2E;
#endif
}
__device__ __forceinline__ float wave_shr1(float x, float fill) {
#if defined(__has_builtin)
#if __has_builtin(__builtin_amdgcn_update_dpp)
  int r = __builtin_amdgcn_update_dpp(__float_as_int(fill), __float_as_int(x),
                                      0x138 /*wave_shr:1*/, 0xf, 0xf, false);
  return __int_as_float(r);
#else
  return __shfl_up(x, 1);
#endif
#else
  return __shfl_up(x, 1);
#endif
}

// async global->LDS, 16B per lane (dest = wave-uniform base + lane*16)
__device__ __forceinline__ void gload_lds16(const _Float16* g, _Float16* l) {
  __builtin_amdgcn_global_load_lds(
      (const __attribute__((address_space(1))) void*)g,
      (__attribute__((address_space(3))) void*)l,
      16, 0, 0);
}

// ---------------- fused fp32->fp16 (enc + W) + zero out/psum ----------------------
__global__ void k_f2h2(const float* __restrict__ enc, const float* __restrict__ W,
                       _Float16* __restrict__ ench, _Float16* __restrict__ wh,
                       float* z, float* psum) {
  int i = blockIdx.x * blockDim.x + threadIdx.x;
  if (i == 0) z[0] = 0.0f;
  if (i < M_ROWS) psum[i] = 0.0f;
  if (i < 512000) {
    float4 v = ((const float4*)enc)[i];
    half4v o = {(_Float16)v.x, (_Float16)v.y, (_Float16)v.z, (_Float16)v.w};
    ((half4v*)ench)[i] = o;
  } else {
    int k = i - 512000;
    if (k < 320000) {
      float4 v = ((const float4*)W)[k];
      half4v o = {(_Float16)v.x, (_Float16)v.y, (_Float16)v.z, (_Float16)v.w};
      ((half4v*)wh)[k] = o;
    }
  }
}

// ---------------- MFMA GEMM + fused sumexp + ballot label-logit scatter ------------
// R20 = R17/R19 (best measured, twice-verified: gemm ~48.7us) with ONE reorder
// inside the existing fences: MFMA cluster moved BEFORE the WAR barrier.
// Old order forced [all 8 ds_reads drain (lgkmcnt(0)+sched_barrier)] -> barrier
// -> stage -> [16 MFMA]: per kk the LDS-read phase (~2050cy/CU, 256KB @128B/cy)
// and the MFMA phase (~2050cy matrix pipe) SERIALIZE, for every wave in
// lockstep -- consistent with 49us vs ~14us modeled. New order lets the
// compiler interleave ds_read with MFMA via its own counted lgkmcnt(N)
// (which it does well when not pinned): vmcnt -> barrier -> {ds_reads + MFMA
// interleaved} -> lgkmcnt(0) -> barrier(WAR) -> stage(kk+2).
// Hazards: reads complete before the WAR barrier (lgkmcnt(0), trivially true
// post-MFMA); stage->wait distance still 1+ full iteration (>> L2 latency).
// Geometry/swizzle/epilogues byte-identical to R17.
__global__ __launch_bounds__(1024) void k_gemm_lse(
    const _Float16* __restrict__ A, const _Float16* __restrict__ Bm,
    const float* __restrict__ bias, const int* __restrict__ y,
    float* __restrict__ psum, float* __restrict__ lgT) {
  __shared__ _Float16 As[2 * 256 * 32];   // 32 KB (2 buffers)
  __shared__ _Float16 Bs[2 * 256 * 32];   // 32 KB
  __shared__ float sPS[4 * 256];          // 4 KB: per-wave_n partial row sums

  const int tid = threadIdx.x;
  const int lane = tid & 63;
  const int wid = tid >> 6;                        // 0..15
  const int wave_m = wid & 3, wave_n = wid >> 2;   // 4x4 waves of 64x64
  const int l15 = lane & 15, quad = lane >> 4;

  // XCD swizzle (8 XCDs, 640 % 8 == 0 -> bijective)
  const int flat = blockIdx.x;
  const int wg = (flat & 7) * 80 + (flat >> 3);
  const int n0 = (wg % 20) * 256;
  const int m0 = (wg / 20) * 256;

  floatx4 acc[4][4];
  floatx4 zz = {0.f, 0.f, 0.f, 0.f};
  #pragma unroll
  for (int mi = 0; mi < 4; ++mi)
    #pragma unroll
    for (int ni = 0; ni < 4; ++ni) acc[mi][ni] = zz;

  // staging geometry (BK=32): one gload_lds16 covers 16 rows x 4 chunks (1 KB).
  // Lane l -> dest slot (row = g*16 + (l>>2), chunk = l&3); slot (row,c) holds
  // global chunk c ^ ((row>>1)&3) via pre-swizzled SOURCE chunk.
  const int lrow = lane >> 2;                              // row within 16-row group
  const int co = (((lane & 3) ^ ((lane >> 3) & 3)) * 8);   // swizzled src chunk (halfs)
  const int rsw2 = (l15 >> 1) & 3;                         // reader chunk XOR

  auto stage = [&](int kk, int buf) {
    {                                      // A: 16 groups of 16 rows / 16 waves
      const int g = wid;
      const int r = g * 16 + lrow;
      int ga = m0 + r; if (ga > M_ROWS - 1) ga = M_ROWS - 1;
      gload_lds16(A + (size_t)ga * K_DIM + kk * 32 + co, As + buf * 8192 + g * 512);
    }
    {                                      // B: 16 groups / 16 waves
      const int g = wid;
      const int r = g * 16 + lrow;
      int gb = n0 + r; if (gb > N_COLS - 1) gb = N_COLS - 1;
      gload_lds16(Bm + (size_t)gb * K_DIM + kk * 32 + co, Bs + buf * 8192 + g * 512);
    }
  };

  // prologue: tiles 0 and 1 in flight (2 vm-ops each per wave)
  stage(0, 0);
  stage(1, 1);

  #pragma unroll
  for (int kk = 0; kk < 8; ++kk) {
    const int cur = kk & 1;
    if (kk < 7) asm volatile("s_waitcnt vmcnt(2)" ::: "memory");  // tile kk landed
    else        asm volatile("s_waitcnt vmcnt(0)" ::: "memory");  // last tile
    __builtin_amdgcn_s_barrier();          // all waves: tile kk resident

    half8 af[4], bf[4];
    #pragma unroll
    for (int mi = 0; mi < 4; ++mi)
      af[mi] = *(const half8*)(As + cur * 8192 + (wave_m * 64 + mi * 16 + l15) * 32 + ((quad ^ rsw2) << 3));
    #pragma unroll
    for (int ni = 0; ni < 4; ++ni)
      bf[ni] = *(const half8*)(Bs + cur * 8192 + (wave_n * 64 + ni * 16 + l15) * 32 + ((quad ^ rsw2) << 3));

    // MFMA BEFORE the WAR barrier: compiler interleaves ds_read<->MFMA with its
    // own counted lgkmcnt(N) (LDS pipe and matrix pipe overlap per wave).
    #pragma unroll
    for (int mi = 0; mi < 4; ++mi)
      #pragma unroll
      for (int ni = 0; ni < 4; ++ni)
        acc[mi][ni] = __builtin_amdgcn_mfma_f32_16x16x32_f16(af[mi], bf[ni], acc[mi][ni], 0, 0, 0);

    asm volatile("s_waitcnt lgkmcnt(0)" ::: "memory");  // all my reads of buf cur done
    __builtin_amdgcn_s_barrier();          // WAR fence: ALL waves done reading buf cur
    if (kk < 6) stage(kk + 2, cur);        // overwrite cur; waited >=1 full iter later
  }

  // ---- epilogue 1: bias + column masks ----
  float bvv[4]; bool cok[4];
  #pragma unroll
  for (int ni = 0; ni < 4; ++ni) {
    int col = n0 + wave_n * 64 + ni * 16 + l15;
    cok[ni] = (col < N_COLS);
    bvv[ni] = cok[ni] ? bias[col] : 0.f;
  }

  // ---- epilogue 2: ballot-based scatter of label logits -------------------------
  // lane j (0..50) holds ext-label j's vocab id (j=0 blank). One ballot finds
  // which labels land in this wave's 64-col window; loop only over matches.
  // C/D layout: col = lane&15, row = quad*4 + reg.
  const int nbase = n0 + wave_n * 64;
  const int mbase = m0 + wave_m * 64;
  int b_lo = mbase / T_LEN;
  int b_hi = (mbase + 63) / T_LEN;
  if (b_hi > B_SZ - 1) b_hi = B_SZ - 1;
  for (int b = b_lo; b <= b_hi; ++b) {
    int v_l = 0x40000000;
    if (lane <= 50) v_l = (lane == 0) ? 0 : y[b * L_LAB + lane - 1];
    int dv_l = v_l - nbase;
    unsigned long long mask = __ballot(dv_l >= 0 && dv_l < 64);
    while (mask) {
      int j = (int)__builtin_ctzll(mask);
      mask &= mask - 1;
      int dv = __shfl(dv_l, j);          // wave-uniform
      int ni = dv >> 4;
      float bb = bvv[0];
      bb = (ni == 1) ? bvv[1] : bb;
      bb = (ni == 2) ? bvv[2] : bb;
      bb = (ni == 3) ? bvv[3] : bb;
      if ((dv & 15) == l15) {
        #pragma unroll
        for (int mi = 0; mi < 4; ++mi) {
          #pragma unroll
          for (int r = 0; r < 4; ++r) {
            float val = acc[mi][0][r];
            val = (ni == 1) ? acc[mi][1][r] : val;
            val = (ni == 2) ? acc[mi][2][r] : val;
            val = (ni == 3) ? acc[mi][3][r] : val;
            int grow = mbase + mi * 16 + quad * 4 + r;
            int t = grow - b * T_LEN;
            if (t >= 0 && t < T_LEN && grow < M_ROWS)
              lgT[((size_t)b * 51 + j) * T_PAD + t] = val + bb;
          }
        }
      }
    }
  }

  // ---- epilogue 3: per-row sum of 2^(logit*log2e) -------------------------------
  // Partial per wave_n -> LDS pre-reduce (disjoint writes) -> ONE atomic per row
  // per block (640K -> 160K device atomics). No max subtraction: logits are
  // O(+-10), 2^(x*log2e) is fp32-safe.
  #pragma unroll
  for (int mi = 0; mi < 4; ++mi) {
    #pragma unroll
    for (int r = 0; r < 4; ++r) {
      int rw = wave_m * 64 + mi * 16 + quad * 4 + r;   // row within 256-tile
      float se = 0.f;
      se += cok[0] ? fexp2((acc[mi][0][r] + bvv[0]) * LOG2E) : 0.f;
      se += cok[1] ? fexp2((acc[mi][1][r] + bvv[1]) * LOG2E) : 0.f;
      se += cok[2] ? fexp2((acc[mi][2][r] + bvv[2]) * LOG2E) : 0.f;
      se += cok[3] ? fexp2((acc[mi][3][r] + bvv[3]) * LOG2E) : 0.f;
      #pragma unroll
      for (int d = 1; d < 16; d <<= 1) se += __shfl_xor(se, d);
      if (l15 == 0) sPS[wave_n * 256 + rw] = se;       // disjoint (wave_n, rw)
    }
  }
  __syncthreads();
  if (tid < 256) {
    int grow = m0 + tid;
    if (grow < M_ROWS) {
      float s = sPS[tid] + sPS[256 + tid] + sPS[512 + tid] + sPS[768 + tid];
      atomicAdd(&psum[grow], s);
    }
  }
}

// ---------------- CTC forward DP + fused lse sum ----------------------------------
// One block (256 thr) per batch element. All waves stage lgT[b] into LDS and
// compute sum_t log2(psum[b,t]) in parallel; wave 0 then runs the serial DP in
// base-2 domain out of LDS. (Log-domain: cross-lane alpha dynamic range
// exceeds fp32 -- prob-domain with uniform rescale measured absmax=inf, R15.)
__global__ __launch_bounds__(256) void k_dp(
    const float* __restrict__ lgT, const float* __restrict__ psum,
    const int* __restrict__ enc_lens, const int* __restrict__ y,
    const int* __restrict__ y_lens, float* __restrict__ out) {
  __shared__ float sA[51 * DP_STR];   // ~105 KB
  __shared__ float sRed[5];
  const int b = blockIdx.x, tid = threadIdx.x;
  const int Tb = enc_lens[b], yl = y_lens[b];

  // stage logits (scaled to base-2 domain)
  const float* g = lgT + (size_t)b * 51 * T_PAD;
  #pragma unroll
  for (int k = 0; k < 26; ++k) {
    int idx = tid + k * 256;
    if (idx < 51 * 128) {
      int row = idx >> 7, c4 = (idx & 127) << 2;
      float4 v = *(const float4*)(g + (size_t)row * T_PAD + c4);
      float4 s = {v.x * LOG2E, v.y * LOG2E, v.z * LOG2E, v.w * LOG2E};
      *(float4*)(sA + row * DP_STR + c4) = s;
    }
  }

  // parallel lse sum: sum_t log2(psum[b,t]), t < Tb
  float sl2 = 0.f;
  for (int t = tid; t < Tb; t += 256) sl2 += flog2(psum[b * T_LEN + t]);
  #pragma unroll
  for (int d = 1; d < 64; d <<= 1) sl2 += __shfl_xor(sl2, d);
  if ((tid & 63) == 0) sRed[1 + (tid >> 6)] = sl2;
  __syncthreads();
  const float slse = LN2 * (sRed[1] + sRed[2] + sRed[3] + sRed[4]);

  if (tid < 64) {
    const int i = tid;
    const int jj = (i + 1 < 50) ? (i + 1) : 50;
    const float* bl = sA;
    const float* ow = sA + jj * DP_STR;
    const bool v0 = (i <= 50), v1 = (i <= 49);
    const bool lane0 = (i == 0);
    const bool skip1 = (i >= 1 && i <= 49) && (y[b * L_LAB + i] != y[b * L_LAB + i - 1]);

    float4 A0 = *(const float4*)(bl + 0),  A1 = *(const float4*)(ow + 0);
    float4 B0 = *(const float4*)(bl + 4),  B1 = *(const float4*)(ow + 4);
    float4 C0 = *(const float4*)(bl + 8),  C1 = *(const float4*)(ow + 8);
    float4 D0 = *(const float4*)(bl + 12), D1 = *(const float4*)(ow + 12);
    const float4 n4 = {NEG, NEG, NEG, NEG};
    if (!v1) { A1 = n4; B1 = n4; C1 = n4; D1 = n4; }

    float a0 = lane0 ? A0.x : NEG;
    float a1 = lane0 ? A1.x : NEG;

    auto step = [&](float l0r, float l1) {
      float l0 = v0 ? l0r : NEG;
      float p1 = wave_shr1(a1, NEG);
      p1 = lane0 ? NEG : p1;
      float th = skip1 ? p1 : NEG;
      float m0 = fmaxf(a0, p1);
      float na0 = m0 + flog2(fexp2(a0 - m0) + fexp2(p1 - m0)) + l0;
      float m1 = fmaxf(fmaxf(a1, a0), th);
      float na1 = m1 + flog2(fexp2(a1 - m1) + fexp2(a0 - m1) + fexp2(th - m1)) + l1;
      a0 = na0; a1 = na1;
    };

    step(A0.y, A1.y);
    step(A0.z, A1.z);
    step(A0.w, A1.w);

    float4 c0 = B0, c1 = B1, n0v = C0, n1v = C1, nn0 = D0, nn1 = D1;
    int t = 4;
    while (t + 4 <= Tb) {
      float4 p0 = *(const float4*)(bl + t + 12);   // max 511 < 512 in-bounds
      float4 p1v = *(const float4*)(ow + t + 12);
      if (!v1) p1v = n4;
      step(c0.x, c1.x);
      step(c0.y, c1.y);
      step(c0.z, c1.z);
      step(c0.w, c1.w);
      c0 = n0v; c1 = n1v; n0v = nn0; n1v = nn1; nn0 = p0; nn1 = p1v;
      t += 4;
    }
    if (t < Tb) { step(c0.x, c1.x); ++t; }
    if (t < Tb) { step(c0.y, c1.y); ++t; }
    if (t < Tb) { step(c0.z, c1.z); ++t; }

    float ea = __shfl(a0, yl);       // s = 2*yl
    float eb = __shfl(a1, yl - 1);   // s = 2*yl-1
    if (lane0) {
      float m = fmaxf(ea, eb);
      float fin = LN2 * (m + flog2(fexp2(ea - m) + fexp2(eb - m)));
      atomicAdd(out, (slse - fin) * (1.0f / (float)B_SZ));
    }
  }
}

extern "C" void kernel_launch(void* const* d_in, const int* in_sizes, int n_in,
                              void* d_out, int out_size, void* d_ws, size_t ws_size,
                              hipStream_t stream) {
  (void)in_sizes; (void)n_in; (void)out_size; (void)ws_size;
  const float* enc      = (const float*)d_in[0];   // [16][500][256]
  const int*   enc_lens = (const int*)d_in[1];     // [16]
  const int*   y        = (const int*)d_in[2];     // [16][50]
  const int*   y_lens   = (const int*)d_in[3];     // [16]
  const float* W        = (const float*)d_in[4];   // [5000][256]
  const float* bias     = (const float*)d_in[5];   // [5000]
  float* out = (float*)d_out;

  char* ws = (char*)d_ws;
  _Float16* ench = (_Float16*)(ws + 0);            // 4,096,000 B
  _Float16* wh   = (_Float16*)(ws + 4096000);      // 2,560,000 B
  float* psum    = (float*)(ws + 6656000);         //    32,000 B
  float* lgT     = (float*)(ws + 6688000);         // 16*51*512*4 = 1,671,168 B

  k_f2h2<<<3250, 256, 0, stream>>>(enc, W, ench, wh, out, psum);
  k_gemm_lse<<<640, 1024, 0, stream>>>(ench, wh, bias, y, psum, lgT);
  k_dp<<<16, 256, 0, stream>>>(lgT, psum, enc_lens, y, y_lens, out);
}

// Round 19
// 153.791 us; speedup vs baseline: 1.0846x; 1.0056x over previous
//
#include <hip/hip_runtime.h>
#include <hip/hip_bf16.h>

#define NEG (-1e30f)
#define M_ROWS 8000   // B*T = 16*500
#define N_COLS 5000   // V
#define K_DIM  256    // D
#define T_LEN  500
#define T_PAD  512    // lgT inner stride (t)
#define B_SZ   16
#define L_LAB  50
#define DP_STR  516   // k_dp LDS row stride (dwords)
#define LOG2E   1.4426950408889634f
#define LN2     0.6931471805599453f

typedef _Float16 half8  __attribute__((ext_vector_type(8)));
typedef _Float16 half4v __attribute__((ext_vector_type(4)));
typedef float    floatx4 __attribute__((ext_vector_type(4)));

__device__ __forceinline__ float fexp2(float x) {
#if defined(__has_builtin)
#if __has_builtin(__builtin_amdgcn_exp2f)
  return __builtin_amdgcn_exp2f(x);
#else
  return __expf(x * LN2);
#endif
#else
  return __expf(x * LN2);
#endif
}
__device__ __forceinline__ float flog2(float x) {
#if defined(__has_builtin)
#if __has_builtin(__builtin_amdgcn_logf)
  return __builtin_amdgcn_logf(x);
#else
  return __logf(x) * LOG2E;
#endif
#else
  return __logf(x) * LOG2E;
#endif
}
__device__ __forceinline__ float wave_shr1(float x, float fill) {
#if defined(__has_builtin)
#if __has_builtin(__builtin_amdgcn_update_dpp)
  int r = __builtin_amdgcn_update_dpp(__float_as_int(fill), __float_as_int(x),
                                      0x138 /*wave_shr:1*/, 0xf, 0xf, false);
  return __int_as_float(r);
#else
  return __shfl_up(x, 1);
#endif
#else
  return __shfl_up(x, 1);
#endif
}

// async global->LDS, 16B per lane (dest = wave-uniform base + lane*16)
__device__ __forceinline__ void gload_lds16(const _Float16* g, _Float16* l) {
  __builtin_amdgcn_global_load_lds(
      (const __attribute__((address_space(1))) void*)g,
      (__attribute__((address_space(3))) void*)l,
      16, 0, 0);
}

// ---------------- fused fp32->fp16 (enc + W) + zero out/psum ----------------------
__global__ void k_f2h2(const float* __restrict__ enc, const float* __restrict__ W,
                       _Float16* __restrict__ ench, _Float16* __restrict__ wh,
                       float* z, float* psum) {
  int i = blockIdx.x * blockDim.x + threadIdx.x;
  if (i == 0) z[0] = 0.0f;
  if (i < M_ROWS) psum[i] = 0.0f;
  if (i < 512000) {
    float4 v = ((const float4*)enc)[i];
    half4v o = {(_Float16)v.x, (_Float16)v.y, (_Float16)v.z, (_Float16)v.w};
    ((half4v*)ench)[i] = o;
  } else {
    int k = i - 512000;
    if (k < 320000) {
      float4 v = ((const float4*)W)[k];
      half4v o = {(_Float16)v.x, (_Float16)v.y, (_Float16)v.z, (_Float16)v.w};
      ((half4v*)wh)[k] = o;
    }
  }
}

// ---------------- MFMA GEMM + fused sumexp + ballot label-logit scatter ------------
// R21 = R20 (gemm 44.3us: ds_read<->MFMA interleave before the WAR barrier)
// + split-MFMA hybrid: 8 MFMAs (mi=0,1) interleave with the 8 ds_reads, then
// lgkmcnt(0) + WAR barrier + stage(kk+2) (issued ~1000cy earlier than R20),
// then the remaining 8 MFMAs (mi=2,3) hide the stage-issue VALU + first part
// of load latency. Captures R17's early-stage AND R20's interleave.
// Hazards unchanged: all my ds_reads drain before the WAR barrier; stage ->
// vmcnt(2) wait distance still >= 1 full iteration.
// Profile note (R20 pass): a 44us 262MB __amd_rocclr_fillBufferAligned
// (harness workspace reset) is a fixed chunk of the non-gemm time.
__global__ __launch_bounds__(1024) void k_gemm_lse(
    const _Float16* __restrict__ A, const _Float16* __restrict__ Bm,
    const float* __restrict__ bias, const int* __restrict__ y,
    float* __restrict__ psum, float* __restrict__ lgT) {
  __shared__ _Float16 As[2 * 256 * 32];   // 32 KB (2 buffers)
  __shared__ _Float16 Bs[2 * 256 * 32];   // 32 KB
  __shared__ float sPS[4 * 256];          // 4 KB: per-wave_n partial row sums

  const int tid = threadIdx.x;
  const int lane = tid & 63;
  const int wid = tid >> 6;                        // 0..15
  const int wave_m = wid & 3, wave_n = wid >> 2;   // 4x4 waves of 64x64
  const int l15 = lane & 15, quad = lane >> 4;

  // XCD swizzle (8 XCDs, 640 % 8 == 0 -> bijective)
  const int flat = blockIdx.x;
  const int wg = (flat & 7) * 80 + (flat >> 3);
  const int n0 = (wg % 20) * 256;
  const int m0 = (wg / 20) * 256;

  floatx4 acc[4][4];
  floatx4 zz = {0.f, 0.f, 0.f, 0.f};
  #pragma unroll
  for (int mi = 0; mi < 4; ++mi)
    #pragma unroll
    for (int ni = 0; ni < 4; ++ni) acc[mi][ni] = zz;

  // staging geometry (BK=32): one gload_lds16 covers 16 rows x 4 chunks (1 KB).
  // Lane l -> dest slot (row = g*16 + (l>>2), chunk = l&3); slot (row,c) holds
  // global chunk c ^ ((row>>1)&3) via pre-swizzled SOURCE chunk.
  const int lrow = lane >> 2;                              // row within 16-row group
  const int co = (((lane & 3) ^ ((lane >> 3) & 3)) * 8);   // swizzled src chunk (halfs)
  const int rsw2 = (l15 >> 1) & 3;                         // reader chunk XOR

  auto stage = [&](int kk, int buf) {
    {                                      // A: 16 groups of 16 rows / 16 waves
      const int g = wid;
      const int r = g * 16 + lrow;
      int ga = m0 + r; if (ga > M_ROWS - 1) ga = M_ROWS - 1;
      gload_lds16(A + (size_t)ga * K_DIM + kk * 32 + co, As + buf * 8192 + g * 512);
    }
    {                                      // B: 16 groups / 16 waves
      const int g = wid;
      const int r = g * 16 + lrow;
      int gb = n0 + r; if (gb > N_COLS - 1) gb = N_COLS - 1;
      gload_lds16(Bm + (size_t)gb * K_DIM + kk * 32 + co, Bs + buf * 8192 + g * 512);
    }
  };

  // prologue: tiles 0 and 1 in flight (2 vm-ops each per wave)
  stage(0, 0);
  stage(1, 1);

  #pragma unroll
  for (int kk = 0; kk < 8; ++kk) {
    const int cur = kk & 1;
    if (kk < 7) asm volatile("s_waitcnt vmcnt(2)" ::: "memory");  // tile kk landed
    else        asm volatile("s_waitcnt vmcnt(0)" ::: "memory");  // last tile
    __builtin_amdgcn_s_barrier();          // all waves: tile kk resident

    half8 af[4], bf[4];
    #pragma unroll
    for (int mi = 0; mi < 4; ++mi)
      af[mi] = *(const half8*)(As + cur * 8192 + (wave_m * 64 + mi * 16 + l15) * 32 + ((quad ^ rsw2) << 3));
    #pragma unroll
    for (int ni = 0; ni < 4; ++ni)
      bf[ni] = *(const half8*)(Bs + cur * 8192 + (wave_n * 64 + ni * 16 + l15) * 32 + ((quad ^ rsw2) << 3));

    // first half: 8 MFMAs interleave with the ds_reads (compiler counted lgkmcnt)
    #pragma unroll
    for (int mi = 0; mi < 2; ++mi)
      #pragma unroll
      for (int ni = 0; ni < 4; ++ni)
        acc[mi][ni] = __builtin_amdgcn_mfma_f32_16x16x32_f16(af[mi], bf[ni], acc[mi][ni], 0, 0, 0);

    asm volatile("s_waitcnt lgkmcnt(0)" ::: "memory");  // all my reads of buf cur done
    __builtin_amdgcn_s_barrier();          // WAR fence: ALL waves done reading buf cur
    if (kk < 6) stage(kk + 2, cur);        // stage early; hidden under second half

    // second half: 8 MFMAs cover stage-issue VALU + load latency
    #pragma unroll
    for (int mi = 2; mi < 4; ++mi)
      #pragma unroll
      for (int ni = 0; ni < 4; ++ni)
        acc[mi][ni] = __builtin_amdgcn_mfma_f32_16x16x32_f16(af[mi], bf[ni], acc[mi][ni], 0, 0, 0);
  }

  // ---- epilogue 1: bias + column masks ----
  float bvv[4]; bool cok[4];
  #pragma unroll
  for (int ni = 0; ni < 4; ++ni) {
    int col = n0 + wave_n * 64 + ni * 16 + l15;
    cok[ni] = (col < N_COLS);
    bvv[ni] = cok[ni] ? bias[col] : 0.f;
  }

  // ---- epilogue 2: ballot-based scatter of label logits -------------------------
  // lane j (0..50) holds ext-label j's vocab id (j=0 blank). One ballot finds
  // which labels land in this wave's 64-col window; loop only over matches.
  // C/D layout: col = lane&15, row = quad*4 + reg.
  const int nbase = n0 + wave_n * 64;
  const int mbase = m0 + wave_m * 64;
  int b_lo = mbase / T_LEN;
  int b_hi = (mbase + 63) / T_LEN;
  if (b_hi > B_SZ - 1) b_hi = B_SZ - 1;
  for (int b = b_lo; b <= b_hi; ++b) {
    int v_l = 0x40000000;
    if (lane <= 50) v_l = (lane == 0) ? 0 : y[b * L_LAB + lane - 1];
    int dv_l = v_l - nbase;
    unsigned long long mask = __ballot(dv_l >= 0 && dv_l < 64);
    while (mask) {
      int j = (int)__builtin_ctzll(mask);
      mask &= mask - 1;
      int dv = __shfl(dv_l, j);          // wave-uniform
      int ni = dv >> 4;
      float bb = bvv[0];
      bb = (ni == 1) ? bvv[1] : bb;
      bb = (ni == 2) ? bvv[2] : bb;
      bb = (ni == 3) ? bvv[3] : bb;
      if ((dv & 15) == l15) {
        #pragma unroll
        for (int mi = 0; mi < 4; ++mi) {
          #pragma unroll
          for (int r = 0; r < 4; ++r) {
            float val = acc[mi][0][r];
            val = (ni == 1) ? acc[mi][1][r] : val;
            val = (ni == 2) ? acc[mi][2][r] : val;
            val = (ni == 3) ? acc[mi][3][r] : val;
            int grow = mbase + mi * 16 + quad * 4 + r;
            int t = grow - b * T_LEN;
            if (t >= 0 && t < T_LEN && grow < M_ROWS)
              lgT[((size_t)b * 51 + j) * T_PAD + t] = val + bb;
          }
        }
      }
    }
  }

  // ---- epilogue 3: per-row sum of 2^(logit*log2e) -------------------------------
  // Partial per wave_n -> LDS pre-reduce (disjoint writes) -> ONE atomic per row
  // per block (640K -> 160K device atomics). No max subtraction: logits are
  // O(+-10), 2^(x*log2e) is fp32-safe.
  #pragma unroll
  for (int mi = 0; mi < 4; ++mi) {
    #pragma unroll
    for (int r = 0; r < 4; ++r) {
      int rw = wave_m * 64 + mi * 16 + quad * 4 + r;   // row within 256-tile
      float se = 0.f;
      se += cok[0] ? fexp2((acc[mi][0][r] + bvv[0]) * LOG2E) : 0.f;
      se += cok[1] ? fexp2((acc[mi][1][r] + bvv[1]) * LOG2E) : 0.f;
      se += cok[2] ? fexp2((acc[mi][2][r] + bvv[2]) * LOG2E) : 0.f;
      se += cok[3] ? fexp2((acc[mi][3][r] + bvv[3]) * LOG2E) : 0.f;
      #pragma unroll
      for (int d = 1; d < 16; d <<= 1) se += __shfl_xor(se, d);
      if (l15 == 0) sPS[wave_n * 256 + rw] = se;       // disjoint (wave_n, rw)
    }
  }
  __syncthreads();
  if (tid < 256) {
    int grow = m0 + tid;
    if (grow < M_ROWS) {
      float s = sPS[tid] + sPS[256 + tid] + sPS[512 + tid] + sPS[768 + tid];
      atomicAdd(&psum[grow], s);
    }
  }
}

// ---------------- CTC forward DP + fused lse sum ----------------------------------
// One block (256 thr) per batch element. All waves stage lgT[b] into LDS and
// compute sum_t log2(psum[b,t]) in parallel; wave 0 then runs the serial DP in
// base-2 domain out of LDS. (Log-domain: cross-lane alpha dynamic range
// exceeds fp32 -- prob-domain with uniform rescale measured absmax=inf, R15.)
__global__ __launch_bounds__(256) void k_dp(
    const float* __restrict__ lgT, const float* __restrict__ psum,
    const int* __restrict__ enc_lens, const int* __restrict__ y,
    const int* __restrict__ y_lens, float* __restrict__ out) {
  __shared__ float sA[51 * DP_STR];   // ~105 KB
  __shared__ float sRed[5];
  const int b = blockIdx.x, tid = threadIdx.x;
  const int Tb = enc_lens[b], yl = y_lens[b];

  // stage logits (scaled to base-2 domain)
  const float* g = lgT + (size_t)b * 51 * T_PAD;
  #pragma unroll
  for (int k = 0; k < 26; ++k) {
    int idx = tid + k * 256;
    if (idx < 51 * 128) {
      int row = idx >> 7, c4 = (idx & 127) << 2;
      float4 v = *(const float4*)(g + (size_t)row * T_PAD + c4);
      float4 s = {v.x * LOG2E, v.y * LOG2E, v.z * LOG2E, v.w * LOG2E};
      *(float4*)(sA + row * DP_STR + c4) = s;
    }
  }

  // parallel lse sum: sum_t log2(psum[b,t]), t < Tb
  float sl2 = 0.f;
  for (int t = tid; t < Tb; t += 256) sl2 += flog2(psum[b * T_LEN + t]);
  #pragma unroll
  for (int d = 1; d < 64; d <<= 1) sl2 += __shfl_xor(sl2, d);
  if ((tid & 63) == 0) sRed[1 + (tid >> 6)] = sl2;
  __syncthreads();
  const float slse = LN2 * (sRed[1] + sRed[2] + sRed[3] + sRed[4]);

  if (tid < 64) {
    const int i = tid;
    const int jj = (i + 1 < 50) ? (i + 1) : 50;
    const float* bl = sA;
    const float* ow = sA + jj * DP_STR;
    const bool v0 = (i <= 50), v1 = (i <= 49);
    const bool lane0 = (i == 0);
    const bool skip1 = (i >= 1 && i <= 49) && (y[b * L_LAB + i] != y[b * L_LAB + i - 1]);

    float4 A0 = *(const float4*)(bl + 0),  A1 = *(const float4*)(ow + 0);
    float4 B0 = *(const float4*)(bl + 4),  B1 = *(const float4*)(ow + 4);
    float4 C0 = *(const float4*)(bl + 8),  C1 = *(const float4*)(ow + 8);
    float4 D0 = *(const float4*)(bl + 12), D1 = *(const float4*)(ow + 12);
    const float4 n4 = {NEG, NEG, NEG, NEG};
    if (!v1) { A1 = n4; B1 = n4; C1 = n4; D1 = n4; }

    float a0 = lane0 ? A0.x : NEG;
    float a1 = lane0 ? A1.x : NEG;

    auto step = [&](float l0r, float l1) {
      float l0 = v0 ? l0r : NEG;
      float p1 = wave_shr1(a1, NEG);
      p1 = lane0 ? NEG : p1;
      float th = skip1 ? p1 : NEG;
      float m0 = fmaxf(a0, p1);
      float na0 = m0 + flog2(fexp2(a0 - m0) + fexp2(p1 - m0)) + l0;
      float m1 = fmaxf(fmaxf(a1, a0), th);
      float na1 = m1 + flog2(fexp2(a1 - m1) + fexp2(a0 - m1) + fexp2(th - m1)) + l1;
      a0 = na0; a1 = na1;
    };

    step(A0.y, A1.y);
    step(A0.z, A1.z);
    step(A0.w, A1.w);

    float4 c0 = B0, c1 = B1, n0v = C0, n1v = C1, nn0 = D0, nn1 = D1;
    int t = 4;
    while (t + 4 <= Tb) {
      float4 p0 = *(const float4*)(bl + t + 12);   // max 511 < 512 in-bounds
      float4 p1v = *(const float4*)(ow + t + 12);
      if (!v1) p1v = n4;
      step(c0.x, c1.x);
      step(c0.y, c1.y);
      step(c0.z, c1.z);
      step(c0.w, c1.w);
      c0 = n0v; c1 = n1v; n0v = nn0; n1v = nn1; nn0 = p0; nn1 = p1v;
      t += 4;
    }
    if (t < Tb) { step(c0.x, c1.x); ++t; }
    if (t < Tb) { step(c0.y, c1.y); ++t; }
    if (t < Tb) { step(c0.z, c1.z); ++t; }

    float ea = __shfl(a0, yl);       // s = 2*yl
    float eb = __shfl(a1, yl - 1);   // s = 2*yl-1
    if (lane0) {
      float m = fmaxf(ea, eb);
      float fin = LN2 * (m + flog2(fexp2(ea - m) + fexp2(eb - m)));
      atomicAdd(out, (slse - fin) * (1.0f / (float)B_SZ));
    }
  }
}

extern "C" void kernel_launch(void* const* d_in, const int* in_sizes, int n_in,
                              void* d_out, int out_size, void* d_ws, size_t ws_size,
                              hipStream_t stream) {
  (void)in_sizes; (void)n_in; (void)out_size; (void)ws_size;
  const float* enc      = (const float*)d_in[0];   // [16][500][256]
  const int*   enc_lens = (const int*)d_in[1];     // [16]
  const int*   y        = (const int*)d_in[2];     // [16][50]
  const int*   y_lens   = (const int*)d_in[3];     // [16]
  const float* W        = (const float*)d_in[4];   // [5000][256]
  const float* bias     = (const float*)d_in[5];   // [5000]
  float* out = (float*)d_out;

  char* ws = (char*)d_ws;
  _Float16* ench = (_Float16*)(ws + 0);            // 4,096,000 B
  _Float16* wh   = (_Float16*)(ws + 4096000);      // 2,560,000 B
  float* psum    = (float*)(ws + 6656000);         //    32,000 B
  float* lgT     = (float*)(ws + 6688000);         // 16*51*512*4 = 1,671,168 B

  k_f2h2<<<3250, 256, 0, stream>>>(enc, W, ench, wh, out, psum);
  k_gemm_lse<<<640, 1024, 0, stream>>>(ench, wh, bias, y, psum, lgT);
  k_dp<<<16, 256, 0, stream>>>(lgT, psum, enc_lens, y, y_lens, out);
}